// Round 14
// baseline (97.384 us; speedup 1.0000x reference)
//
#include <hip/hip_runtime.h>

typedef __attribute__((ext_vector_type(8))) _Float16 f16x8_t;  // MFMA A/B operand (4 VGPRs)
typedef __attribute__((ext_vector_type(2))) _Float16 f16x2_t;  // packed f16 pair
typedef __attribute__((ext_vector_type(4))) float f32x4_t;     // MFMA accumulator

#define SLOTS 64
#define OVF_CAP 8192

__device__ __forceinline__ f16x2_t pkh(float lo, float hi) {
    return __builtin_bit_cast(f16x2_t, __builtin_amdgcn_cvt_pkrtz(lo, hi));
}
__device__ __forceinline__ unsigned int pkrtz(float lo, float hi) {
    return __builtin_bit_cast(unsigned int, __builtin_amdgcn_cvt_pkrtz(lo, hi));
}

#define LD4(p) (*reinterpret_cast<const float4*>(p))

__device__ __forceinline__ float4 shfl4(float4 v, int src) {
    float4 r;
    r.x = __shfl(v.x, src); r.y = __shfl(v.y, src);
    r.z = __shfl(v.z, src); r.w = __shfl(v.w, src);
    return r;
}

// ws layout (bytes):
//   [0      .. 19456)   f16 tab: W1p (2KB) + W2p (17KB)
//   [65536  .. 265536)  int cnt[n_nodes]
//   [266240 .. 266244)  int ovf_cnt
//   [266304 .. 299072)  int ovf[OVF_CAP]
//   [524288 .. +12.8MB) int eord[n_nodes][SLOTS]

// ============ kernel 0: {root-init + cnt zero | tab prep + ovf_cnt zero} ============
__global__ __launch_bounds__(256) void prep_kernel(
    const float* __restrict__ x,
    const float* __restrict__ W1,      // [8,32]
    const float* __restrict__ b1,      // [32]
    const float* __restrict__ W2,      // [32,256]
    const float* __restrict__ b2,      // [256]
    const float* __restrict__ rootk,   // [16,16]
    const float* __restrict__ bias,    // [16]
    float* __restrict__ out,           // [N,16]
    _Float16* __restrict__ tab,
    int* __restrict__ cnt,             // may be null (fallback mode)
    int* __restrict__ ovf_cnt,
    int n_nodes, int root_blocks)
{
    const int tid = threadIdx.x;
    const int bid = blockIdx.x;

    if (bid < root_blocks) {
        __shared__ float sR[256];
        __shared__ float sB[16];
        if (tid < 256) sR[tid] = rootk[tid];
        if (tid < 16)  sB[tid] = bias[tid];
        __syncthreads();

        int nid = bid * 256 + tid;
        if (nid >= n_nodes) return;
        if (cnt) cnt[nid] = 0;

        const float* xp = x + (size_t)nid * 16;
        float xf[16];
#pragma unroll
        for (int f = 0; f < 16; f += 4) {
            float4 v = LD4(xp + f);
            xf[f] = v.x; xf[f + 1] = v.y; xf[f + 2] = v.z; xf[f + 3] = v.w;
        }
        float o[16];
#pragma unroll
        for (int cc = 0; cc < 16; ++cc) o[cc] = sB[cc];
#pragma unroll
        for (int f = 0; f < 16; ++f) {
            float p = xf[f];
#pragma unroll
            for (int cc = 0; cc < 16; ++cc)
                o[cc] = fmaf(p, sR[f * 16 + cc], o[cc]);
        }
        float* dst = out + (size_t)nid * 16;
#pragma unroll
        for (int cc = 0; cc < 16; cc += 4)
            *reinterpret_cast<float4*>(dst + cc) = make_float4(o[cc], o[cc+1], o[cc+2], o[cc+3]);
    } else {
        if (tid == 0 && ovf_cnt) *ovf_cnt = 0;
        for (int it = tid; it < 64 * 19; it += 256) {
            int grp  = it >> 6;         // 0,1 -> W1p halves; 2..18 -> W2p steps
            int lane = it & 63;
            int q = lane >> 4, cc = lane & 15;
            union { _Float16 h[8]; uint4 u; } pk;
            if (grp < 2) {
                int hh = grp;
#pragma unroll
                for (int j = 0; j < 8; ++j) {
                    float v = 0.f;
                    if (q == 0)              v = W1[j * 32 + cc + 16 * hh];
                    else if (q == 1 && j==0) v = b1[cc + 16 * hh];
                    pk.h[j] = (_Float16)v;
                }
                *reinterpret_cast<uint4*>(tab + ((size_t)hh * 64 + lane) * 8) = pk.u;
            } else {
                int s = grp - 2;        // K-step
#pragma unroll
                for (int j = 0; j < 8; ++j) {
                    float v;
                    if (s < 16) {
                        int hd = (j < 4) ? (4 * q + j) : (4 * q + 12 + j);  // perm
                        v = W2[hd * 256 + s * 16 + cc];
                    } else {
                        v = (q < 2) ? b2[(q * 8 + j) * 16 + cc] : 0.f;       // b2 fold
                    }
                    pk.h[j] = (_Float16)v;
                }
                *reinterpret_cast<uint4*>(tab + 1024 + ((size_t)s * 64 + lane) * 8) = pk.u;
            }
        }
    }
}

// ============ kernel 1: bucket edges by target ============
__global__ __launch_bounds__(256) void bucket_kernel(
    const int* __restrict__ idx_i,
    int* __restrict__ cnt,
    int* __restrict__ eord,
    int* __restrict__ ovf_cnt,
    int* __restrict__ ovf,
    int n_edges)
{
    int e = blockIdx.x * 256 + threadIdx.x;
    if (e >= n_edges) return;
    int t = idx_i[e];
    int pos = atomicAdd(cnt + t, 1);
    if (pos < SLOTS) {
        eord[(size_t)t * SLOTS + pos] = e;
    } else {
        int o = atomicAdd(ovf_cnt, 1);
        if (o < OVF_CAP) ovf[o] = e;
    }
}

// ============ kernel 2: per-node MFMA — one wave per node, 4 nodes/wave run ============
__global__ __launch_bounds__(256) void node_mfma_kernel(
    const float* __restrict__ x,       // [N,16]
    const float* __restrict__ efeat,   // [E,8]
    const int*   __restrict__ idx_j,
    const _Float16* __restrict__ tab,
    const int*   __restrict__ cnt,
    const int*   __restrict__ eord,
    float* __restrict__ out,           // [N,16], pre-initialized with root term
    int n_nodes)
{
    const int lane = threadIdx.x & 63;
    const int q = lane >> 4;
    const int c = lane & 15;

    // ---- per-wave fragment preload (registers, f16) ----
    const f16x8_t* w1f = reinterpret_cast<const f16x8_t*>(tab) + lane;
    const f16x8_t aW1_0 = w1f[0];
    const f16x8_t aW1_1 = w1f[64];
    const f16x8_t* w2f = reinterpret_cast<const f16x8_t*>(tab + 1024) + lane;
    f16x8_t bW2[17];
#pragma unroll
    for (int s = 0; s < 17; ++s) bW2[s] = w2f[s * 64];

    const unsigned int c1 = (q == 1) ? 0x00003C00u : 0u;   // f16(1.0) one-hot for b1 row
    const bool isq0 = (q == 0);
    const bool qodd = (q & 1);

    const int wid = blockIdx.x * 4 + (threadIdx.x >> 6);
    const int n0 = wid * 4;
    if (n0 >= n_nodes) return;

    for (int nn = 0; nn < 4; ++nn) {
        const int n = n0 + nn;
        if (n >= n_nodes) break;
        const int deg = cnt[n];
        if (deg <= 0) continue;
        const int degc = (deg < SLOTS) ? deg : SLOTS;

        const int* ebase = eord + (size_t)n * SLOTS;

        f32x4_t acc0 = {0.f, 0.f, 0.f, 0.f};
        f32x4_t acc1 = {0.f, 0.f, 0.f, 0.f};

        for (int k0 = 0; k0 < degc; k0 += 16) {
            const int k = k0 + c;
            const bool valid = (k < degc);
            const int eid = valid ? ebase[k] : ebase[0];
            const int j = idx_j[eid];

            // x quarter load + redistribute (row c's 16 floats)
            float4 XQ = LD4(x + (size_t)j * 16 + q * 4);
            float4 X0 = shfl4(XQ, c);
            float4 X1 = shfl4(XQ, c + 16);
            float4 X2 = shfl4(XQ, c + 32);
            float4 X3 = shfl4(XQ, c + 48);

            // e-features of own row's edge
            const float* ep = efeat + (size_t)eid * 8;
            float4 E0 = LD4(ep), E1 = LD4(ep + 4);

            // ---- h via MFMA (f16) ----
            union { f16x8_t v8; unsigned int u[4]; } bB;
            bB.u[0] = isq0 ? pkrtz(E0.x, E0.y) : c1;
            bB.u[1] = isq0 ? pkrtz(E0.z, E0.w) : 0u;
            bB.u[2] = isq0 ? pkrtz(E1.x, E1.y) : 0u;
            bB.u[3] = isq0 ? pkrtz(E1.z, E1.w) : 0u;

            f32x4_t z4 = {0.f, 0.f, 0.f, 0.f};
            f32x4_t h0 = __builtin_amdgcn_mfma_f32_16x16x32_f16(aW1_0, bB.v8, z4, 0, 0, 0);
            f32x4_t h1 = __builtin_amdgcn_mfma_f32_16x16x32_f16(aW1_1, bB.v8, z4, 0, 0, 0);

            f16x2_t hp0 = pkh(fmaxf(h0[0], 0.f), fmaxf(h0[1], 0.f));
            f16x2_t hp1 = pkh(fmaxf(h0[2], 0.f), fmaxf(h0[3], 0.f));
            f16x2_t hp2 = pkh(fmaxf(h1[0], 0.f), fmaxf(h1[1], 0.f));
            f16x2_t hp3 = pkh(fmaxf(h1[2], 0.f), fmaxf(h1[3], 0.f));

            float xf[16];
            xf[0]=X0.x; xf[1]=X0.y; xf[2]=X0.z; xf[3]=X0.w;
            xf[4]=X1.x; xf[5]=X1.y; xf[6]=X1.z; xf[7]=X1.w;
            xf[8]=X2.x; xf[9]=X2.y; xf[10]=X2.z; xf[11]=X2.w;
            xf[12]=X3.x; xf[13]=X3.y; xf[14]=X3.z; xf[15]=X3.w;
            if (!valid) {
#pragma unroll
                for (int t = 0; t < 16; ++t) xf[t] = 0.f;   // invalid A-row -> 0
            }

            f16x2_t xss[16];
#pragma unroll
            for (int f = 0; f < 16; ++f)
                xss[f] = pkh(xf[f], xf[f]);

            union { f16x8_t v8; unsigned int u[4]; } xb;
            xb.u[0] = pkrtz(qodd ? xf[8]  : xf[0], qodd ? xf[9]  : xf[1]);
            xb.u[1] = pkrtz(qodd ? xf[10] : xf[2], qodd ? xf[11] : xf[3]);
            xb.u[2] = pkrtz(qodd ? xf[12] : xf[4], qodd ? xf[13] : xf[5]);
            xb.u[3] = pkrtz(qodd ? xf[14] : xf[6], qodd ? xf[15] : xf[7]);

            union { f16x8_t v8; f16x2_t v2[4]; } afr;
#pragma unroll
            for (int s = 0; s < 16; s += 2) {
                f16x2_t xs2 = xss[s];
                afr.v2[0] = hp0 * xs2;
                afr.v2[1] = hp1 * xs2;
                afr.v2[2] = hp2 * xs2;
                afr.v2[3] = hp3 * xs2;
                acc0 = __builtin_amdgcn_mfma_f32_16x16x32_f16(afr.v8, bW2[s], acc0, 0, 0, 0);
                xs2 = xss[s + 1];
                afr.v2[0] = hp0 * xs2;
                afr.v2[1] = hp1 * xs2;
                afr.v2[2] = hp2 * xs2;
                afr.v2[3] = hp3 * xs2;
                acc1 = __builtin_amdgcn_mfma_f32_16x16x32_f16(afr.v8, bW2[s + 1], acc1, 0, 0, 0);
            }
            acc0 = __builtin_amdgcn_mfma_f32_16x16x32_f16(xb.v8, bW2[16], acc0, 0, 0, 0);
        }

        // ---- reduce D rows (16 edges) of column c -> one value ----
        float s = (acc0[0] + acc1[0]) + (acc0[1] + acc1[1])
                + (acc0[2] + acc1[2]) + (acc0[3] + acc1[3]);
        s += __shfl_xor(s, 16);
        s += __shfl_xor(s, 32);
        if (lane < 16)
            atomicAdd(out + (size_t)n * 16 + c, s);   // atomic only for ovf-path safety
    }
}

// ============ kernel 3: overflow tail (deg > SLOTS edges) — normally empty ============
__global__ __launch_bounds__(256) void ovf_kernel(
    const float* __restrict__ x,
    const float* __restrict__ efeat,
    const int*   __restrict__ idx_i,
    const int*   __restrict__ idx_j,
    const float* __restrict__ W1, const float* __restrict__ b1,
    const float* __restrict__ W2, const float* __restrict__ b2,
    const int*   __restrict__ ovf_cnt,
    const int*   __restrict__ ovf,
    float* __restrict__ out)
{
    int m = *ovf_cnt;
    if (m > OVF_CAP) m = OVF_CAP;
    if (m <= 0) return;
    for (int it = threadIdx.x; it < m * 16; it += 256) {
        int o = it >> 4, cch = it & 15;
        int e = ovf[o];
        int j = idx_j[e];
        int t = idx_i[e];
        float msg = 0.f;
        for (int hd = 0; hd < 32; ++hd) {
            float h = b1[hd];
            for (int k = 0; k < 8; ++k) h = fmaf(efeat[(size_t)e*8+k], W1[k*32+hd], h);
            h = fmaxf(h, 0.f);
            float dot = 0.f;
            for (int f = 0; f < 16; ++f) dot = fmaf(x[(size_t)j*16+f], W2[hd*256 + f*16 + cch], dot);
            msg = fmaf(h, dot, msg);
        }
        for (int f = 0; f < 16; ++f) msg = fmaf(x[(size_t)j*16+f], b2[f*16+cch], msg);
        atomicAdd(out + (size_t)t * 16 + cch, msg);
    }
}

// ============ fallback: r13 direct-atomic edge kernel (ws too small) ============
template<int EXACT>
__global__ __launch_bounds__(256) void edge_mfma_kernel(
    const float* __restrict__ x, const float* __restrict__ efeat,
    const int* __restrict__ idx_i, const int* __restrict__ idx_j,
    const _Float16* __restrict__ tab, float* __restrict__ out,
    int n_edges, int n_groups)
{
    const int lane = threadIdx.x & 63;
    const int q = lane >> 4;
    const int c = lane & 15;
    const f16x8_t* w1f = reinterpret_cast<const f16x8_t*>(tab) + lane;
    const f16x8_t aW1_0 = w1f[0];
    const f16x8_t aW1_1 = w1f[64];
    const f16x8_t* w2f = reinterpret_cast<const f16x8_t*>(tab + 1024) + lane;
    f16x8_t bW2[17];
#pragma unroll
    for (int s = 0; s < 17; ++s) bW2[s] = w2f[s * 64];
    const unsigned int c1 = (q == 1) ? 0x00003C00u : 0u;
    const bool isq0 = (q == 0);
    const bool qodd = (q & 1);
    float* const outc = out + c;

    for (int g = blockIdx.x * 4 + (threadIdx.x >> 6); g < n_groups; g += gridDim.x * 4) {
        int eid = g * 16 + c;
        bool va = (eid < n_edges);
        int el = va ? eid : (n_edges - 1);
        int j = idx_j[el];
        float4 X0 = LD4(x + (size_t)j*16), X1 = LD4(x + (size_t)j*16 + 4);
        float4 X2 = LD4(x + (size_t)j*16 + 8), X3 = LD4(x + (size_t)j*16 + 12);
        const float* ep = efeat + (size_t)el * 8;
        float4 E0 = LD4(ep), E1 = LD4(ep + 4);
        int t0, t1, t2, t3;
        {
            const int eb = g * 16 + q * 4;
            t0 = (eb + 0 < n_edges) ? idx_i[eb + 0] : 0;
            t1 = (eb + 1 < n_edges) ? idx_i[eb + 1] : 0;
            t2 = (eb + 2 < n_edges) ? idx_i[eb + 2] : 0;
            t3 = (eb + 3 < n_edges) ? idx_i[eb + 3] : 0;
        }
        union { f16x8_t v8; unsigned int u[4]; } bB;
        bB.u[0] = isq0 ? pkrtz(E0.x, E0.y) : c1;
        bB.u[1] = isq0 ? pkrtz(E0.z, E0.w) : 0u;
        bB.u[2] = isq0 ? pkrtz(E1.x, E1.y) : 0u;
        bB.u[3] = isq0 ? pkrtz(E1.z, E1.w) : 0u;
        f32x4_t z4 = {0.f, 0.f, 0.f, 0.f};
        f32x4_t h0 = __builtin_amdgcn_mfma_f32_16x16x32_f16(aW1_0, bB.v8, z4, 0, 0, 0);
        f32x4_t h1 = __builtin_amdgcn_mfma_f32_16x16x32_f16(aW1_1, bB.v8, z4, 0, 0, 0);
        f16x2_t hp0 = pkh(fmaxf(h0[0], 0.f), fmaxf(h0[1], 0.f));
        f16x2_t hp1 = pkh(fmaxf(h0[2], 0.f), fmaxf(h0[3], 0.f));
        f16x2_t hp2 = pkh(fmaxf(h1[0], 0.f), fmaxf(h1[1], 0.f));
        f16x2_t hp3 = pkh(fmaxf(h1[2], 0.f), fmaxf(h1[3], 0.f));
        float xf[16];
        xf[0]=X0.x; xf[1]=X0.y; xf[2]=X0.z; xf[3]=X0.w;
        xf[4]=X1.x; xf[5]=X1.y; xf[6]=X1.z; xf[7]=X1.w;
        xf[8]=X2.x; xf[9]=X2.y; xf[10]=X2.z; xf[11]=X2.w;
        xf[12]=X3.x; xf[13]=X3.y; xf[14]=X3.z; xf[15]=X3.w;
        if (!va) { for (int t = 0; t < 16; ++t) xf[t] = 0.f; }
        f16x2_t xss[16];
#pragma unroll
        for (int f = 0; f < 16; ++f) xss[f] = pkh(xf[f], xf[f]);
        union { f16x8_t v8; unsigned int u[4]; } xb;
        xb.u[0] = pkrtz(qodd ? xf[8]  : xf[0], qodd ? xf[9]  : xf[1]);
        xb.u[1] = pkrtz(qodd ? xf[10] : xf[2], qodd ? xf[11] : xf[3]);
        xb.u[2] = pkrtz(qodd ? xf[12] : xf[4], qodd ? xf[13] : xf[5]);
        xb.u[3] = pkrtz(qodd ? xf[14] : xf[6], qodd ? xf[15] : xf[7]);
        f32x4_t acc0 = {0.f,0.f,0.f,0.f}, acc1 = {0.f,0.f,0.f,0.f};
        union { f16x8_t v8; f16x2_t v2[4]; } afr;
#pragma unroll
        for (int s = 0; s < 16; s += 2) {
            f16x2_t xs2 = xss[s];
            afr.v2[0] = hp0 * xs2; afr.v2[1] = hp1 * xs2;
            afr.v2[2] = hp2 * xs2; afr.v2[3] = hp3 * xs2;
            acc0 = __builtin_amdgcn_mfma_f32_16x16x32_f16(afr.v8, bW2[s], acc0, 0, 0, 0);
            xs2 = xss[s + 1];
            afr.v2[0] = hp0 * xs2; afr.v2[1] = hp1 * xs2;
            afr.v2[2] = hp2 * xs2; afr.v2[3] = hp3 * xs2;
            acc1 = __builtin_amdgcn_mfma_f32_16x16x32_f16(afr.v8, bW2[s + 1], acc1, 0, 0, 0);
        }
        acc0 = __builtin_amdgcn_mfma_f32_16x16x32_f16(xb.v8, bW2[16], acc0, 0, 0, 0);
        const float rr0 = acc0[0] + acc1[0];
        const float rr1 = acc0[1] + acc1[1];
        const float rr2 = acc0[2] + acc1[2];
        const float rr3 = acc0[3] + acc1[3];
        const int eb = g * 16 + q * 4;
        if (eb + 0 < n_edges) atomicAdd(outc + (size_t)t0 * 16, rr0);
        if (eb + 1 < n_edges) atomicAdd(outc + (size_t)t1 * 16, rr1);
        if (eb + 2 < n_edges) atomicAdd(outc + (size_t)t2 * 16, rr2);
        if (eb + 3 < n_edges) atomicAdd(outc + (size_t)t3 * 16, rr3);
    }
}

extern "C" void kernel_launch(void* const* d_in, const int* in_sizes, int n_in,
                              void* d_out, int out_size, void* d_ws, size_t ws_size,
                              hipStream_t stream) {
    const float* x     = (const float*)d_in[0];
    const float* e     = (const float*)d_in[1];
    const int*   idx_i = (const int*)d_in[2];
    const int*   idx_j = (const int*)d_in[3];
    const float* W1    = (const float*)d_in[4];
    const float* b1    = (const float*)d_in[5];
    const float* W2    = (const float*)d_in[6];
    const float* b2    = (const float*)d_in[7];
    const float* rootk = (const float*)d_in[8];
    const float* bias  = (const float*)d_in[9];

    int n_nodes  = in_sizes[0] / 16;
    int n_edges  = in_sizes[2];

    float* out = (float*)d_out;
    _Float16* tab = (_Float16*)d_ws;
    int* cnt     = (int*)((char*)d_ws + 65536);
    int* ovf_cnt = (int*)((char*)d_ws + 266240);
    int* ovf     = (int*)((char*)d_ws + 266304);
    int* eord    = (int*)((char*)d_ws + 524288);

    size_t need = 524288 + (size_t)n_nodes * SLOTS * sizeof(int);
    const int use_bucket = (ws_size >= need) ? 1 : 0;

    int root_blocks = (n_nodes + 255) / 256;
    prep_kernel<<<root_blocks + 1, 256, 0, stream>>>(x, W1, b1, W2, b2, rootk, bias,
                                                     out, tab, use_bucket ? cnt : nullptr,
                                                     use_bucket ? ovf_cnt : nullptr,
                                                     n_nodes, root_blocks);

    if (use_bucket) {
        int bblocks = (n_edges + 255) / 256;
        bucket_kernel<<<bblocks, 256, 0, stream>>>(idx_i, cnt, eord, ovf_cnt, ovf, n_edges);
        int nblocks = (n_nodes + 15) / 16;   // 4 waves/block, 4 nodes/wave
        node_mfma_kernel<<<nblocks, 256, 0, stream>>>(x, e, idx_j, tab, cnt, eord,
                                                      out, n_nodes);
        ovf_kernel<<<1, 256, 0, stream>>>(x, e, idx_i, idx_j, W1, b1, W2, b2,
                                          ovf_cnt, ovf, out);
    } else {
        int n_groups = (n_edges + 15) / 16;
        int blocks = (n_groups + 63) / 64;
        if ((n_edges & 15) == 0)
            edge_mfma_kernel<1><<<blocks * 16, 256, 0, stream>>>(x, e, idx_i, idx_j, tab,
                                                                 out, n_edges, n_groups);
        else
            edge_mfma_kernel<0><<<blocks * 16, 256, 0, stream>>>(x, e, idx_i, idx_j, tab,
                                                                 out, n_edges, n_groups);
    }
}

// Round 15
// 56.158 us; speedup vs baseline: 1.7341x; 1.7341x over previous
//
#include <hip/hip_runtime.h>

typedef __attribute__((ext_vector_type(8))) _Float16 f16x8_t;  // MFMA A/B operand (4 VGPRs)
typedef __attribute__((ext_vector_type(2))) _Float16 f16x2_t;  // packed f16 pair
typedef __attribute__((ext_vector_type(4))) float f32x4_t;     // MFMA accumulator

__device__ __forceinline__ f16x2_t pkh(float lo, float hi) {
    return __builtin_bit_cast(f16x2_t, __builtin_amdgcn_cvt_pkrtz(lo, hi));
}
__device__ __forceinline__ unsigned int pkrtz(float lo, float hi) {
    return __builtin_bit_cast(unsigned int, __builtin_amdgcn_cvt_pkrtz(lo, hi));
}
// duplicate low/high f16 of a packed pair: (x0,x1) -> (x0,x0) / (x1,x1)
__device__ __forceinline__ f16x2_t dup_lo(unsigned int u) {
    return __builtin_bit_cast(f16x2_t, __builtin_amdgcn_perm(u, u, 0x01000100u));
}
__device__ __forceinline__ f16x2_t dup_hi(unsigned int u) {
    return __builtin_bit_cast(f16x2_t, __builtin_amdgcn_perm(u, u, 0x03020302u));
}

#define LD4(p) (*reinterpret_cast<const float4*>(p))

// ws layout (bytes):
//   [0       ..  19456)  f16 tab: W1p (2KB) + W2p (17KB)
//   [1 MB    .. +16 MB)  uint rec32[E][8]  : adjacent f16 pairs of gathered x row
//   [20 MB   .. + 8 MB)  uint ef16[E][4]   : f16 pairs of edge features

// ============ kernel 0: {root-init | tab prep} ============
__global__ __launch_bounds__(256) void prep_kernel(
    const float* __restrict__ x,
    const float* __restrict__ W1,      // [8,32]
    const float* __restrict__ b1,      // [32]
    const float* __restrict__ W2,      // [32,256]
    const float* __restrict__ b2,      // [256]
    const float* __restrict__ rootk,   // [16,16]
    const float* __restrict__ bias,    // [16]
    float* __restrict__ out,           // [N,16]
    _Float16* __restrict__ tab,
    int n_nodes, int root_blocks)
{
    const int tid = threadIdx.x;
    const int bid = blockIdx.x;

    if (bid < root_blocks) {
        __shared__ float sR[256];
        __shared__ float sB[16];
        if (tid < 256) sR[tid] = rootk[tid];
        if (tid < 16)  sB[tid] = bias[tid];
        __syncthreads();

        int nid = bid * 256 + tid;
        if (nid >= n_nodes) return;

        const float* xp = x + (size_t)nid * 16;
        float xf[16];
#pragma unroll
        for (int f = 0; f < 16; f += 4) {
            float4 v = LD4(xp + f);
            xf[f] = v.x; xf[f + 1] = v.y; xf[f + 2] = v.z; xf[f + 3] = v.w;
        }
        float o[16];
#pragma unroll
        for (int cc = 0; cc < 16; ++cc) o[cc] = sB[cc];
#pragma unroll
        for (int f = 0; f < 16; ++f) {
            float p = xf[f];
#pragma unroll
            for (int cc = 0; cc < 16; ++cc)
                o[cc] = fmaf(p, sR[f * 16 + cc], o[cc]);
        }
        float* dst = out + (size_t)nid * 16;
#pragma unroll
        for (int cc = 0; cc < 16; cc += 4)
            *reinterpret_cast<float4*>(dst + cc) = make_float4(o[cc], o[cc+1], o[cc+2], o[cc+3]);
    } else {
        for (int it = tid; it < 64 * 19; it += 256) {
            int grp  = it >> 6;         // 0,1 -> W1p halves; 2..18 -> W2p steps
            int lane = it & 63;
            int q = lane >> 4, cc = lane & 15;
            union { _Float16 h[8]; uint4 u; } pk;
            if (grp < 2) {
                int hh = grp;
#pragma unroll
                for (int j = 0; j < 8; ++j) {
                    float v = 0.f;
                    if (q == 0)              v = W1[j * 32 + cc + 16 * hh];
                    else if (q == 1 && j==0) v = b1[cc + 16 * hh];
                    pk.h[j] = (_Float16)v;
                }
                *reinterpret_cast<uint4*>(tab + ((size_t)hh * 64 + lane) * 8) = pk.u;
            } else {
                int s = grp - 2;        // K-step
#pragma unroll
                for (int j = 0; j < 8; ++j) {
                    float v;
                    if (s < 16) {
                        int hd = (j < 4) ? (4 * q + j) : (4 * q + 12 + j);  // perm
                        v = W2[hd * 256 + s * 16 + cc];
                    } else {
                        v = (q < 2) ? b2[(q * 8 + j) * 16 + cc] : 0.f;       // b2 fold
                    }
                    pk.h[j] = (_Float16)v;
                }
                *reinterpret_cast<uint4*>(tab + 1024 + ((size_t)s * 64 + lane) * 8) = pk.u;
            }
        }
    }
}

// ============ kernel 1: pre-gather + pre-convert (massive TLP, no chains) ============
__global__ __launch_bounds__(256) void prepg_kernel(
    const float* __restrict__ x,       // [N,16]
    const float* __restrict__ efeat,   // [E,8]
    const int*   __restrict__ idx_j,
    unsigned int* __restrict__ rec32,  // [E][8]
    unsigned int* __restrict__ ef16,   // [E][4]
    int n_edges)
{
    int e = blockIdx.x * 256 + threadIdx.x;
    if (e >= n_edges) return;

    const int j = idx_j[e];
    const float* xp = x + (size_t)j * 16;
    float4 x0 = LD4(xp), x1 = LD4(xp + 4), x2 = LD4(xp + 8), x3 = LD4(xp + 12);

    uint4 r0, r1;
    r0.x = pkrtz(x0.x, x0.y); r0.y = pkrtz(x0.z, x0.w);
    r0.z = pkrtz(x1.x, x1.y); r0.w = pkrtz(x1.z, x1.w);
    r1.x = pkrtz(x2.x, x2.y); r1.y = pkrtz(x2.z, x2.w);
    r1.z = pkrtz(x3.x, x3.y); r1.w = pkrtz(x3.z, x3.w);
    uint4* rp = reinterpret_cast<uint4*>(rec32 + (size_t)e * 8);
    rp[0] = r0; rp[1] = r1;

    const float* ep = efeat + (size_t)e * 8;
    float4 e0 = LD4(ep), e1 = LD4(ep + 4);
    uint4 re;
    re.x = pkrtz(e0.x, e0.y); re.y = pkrtz(e0.z, e0.w);
    re.z = pkrtz(e1.x, e1.y); re.w = pkrtz(e1.z, e1.w);
    *reinterpret_cast<uint4*>(ef16 + (size_t)e * 4) = re;
}

// ============ kernel 2: streaming MFMA edge kernel (no indirection, no conversion) ============
template<int EXACT>
__global__ __launch_bounds__(256) void edge_pre_kernel(
    const unsigned int* __restrict__ rec32,  // [E][8]
    const unsigned int* __restrict__ ef16,   // [E][4]
    const int* __restrict__ idx_i,
    const _Float16* __restrict__ tab,
    float* __restrict__ out,                 // [N,16], pre-initialized with root term
    int n_edges, int n_groups)
{
    const int lane = threadIdx.x & 63;
    const int q = lane >> 4;
    const int c = lane & 15;

    // ---- per-wave fragment preload (registers, f16) ----
    const f16x8_t* w1f = reinterpret_cast<const f16x8_t*>(tab) + lane;
    const f16x8_t aW1_0 = w1f[0];
    const f16x8_t aW1_1 = w1f[64];
    const f16x8_t* w2f = reinterpret_cast<const f16x8_t*>(tab + 1024) + lane;
    f16x8_t bW2[17];
#pragma unroll
    for (int s = 0; s < 17; ++s) bW2[s] = w2f[s * 64];

    const unsigned int c1 = (q == 1) ? 0x00003C00u : 0u;   // f16(1.0) one-hot for b1 row
    const bool isq0 = (q == 0);
    const bool qodd = (q & 1);
    float* const outc = out + c;

    const int nwaves = gridDim.x * 4;
    for (int g = blockIdx.x * 4 + (threadIdx.x >> 6); g < n_groups; g += nwaves) {
        int eid = g * 16 + c;
        if (!EXACT) { if (eid >= n_edges) eid = n_edges - 1; }

        // ---- streaming loads: own edge's record + features (all coalesced) ----
        const uint4* rp = reinterpret_cast<const uint4*>(rec32 + (size_t)eid * 8);
        uint4 r0 = rp[0], r1 = rp[1];
        uint4 re = *reinterpret_cast<const uint4*>(ef16 + (size_t)eid * 4);

        int t0, t1, t2, t3;
        {
            int4 tv;
            if (EXACT || (g * 16 + 16 <= n_edges)) {
                tv = *reinterpret_cast<const int4*>(idx_i + g * 16 + q * 4);
            } else {
                const int eb = g * 16 + q * 4;
                tv.x = (eb + 0 < n_edges) ? idx_i[eb + 0] : 0;
                tv.y = (eb + 1 < n_edges) ? idx_i[eb + 1] : 0;
                tv.z = (eb + 2 < n_edges) ? idx_i[eb + 2] : 0;
                tv.w = (eb + 3 < n_edges) ? idx_i[eb + 3] : 0;
            }
            t0 = tv.x; t1 = tv.y; t2 = tv.z; t3 = tv.w;
        }

        unsigned int pr[8] = {r0.x, r0.y, r0.z, r0.w, r1.x, r1.y, r1.z, r1.w};
        if (!EXACT) {
            if (g * 16 + c >= n_edges) {
#pragma unroll
                for (int t = 0; t < 8; ++t) pr[t] = 0u;   // invalid A-row -> zeros
            }
        }

        // ---- h via MFMA (f16): lane owns hd {4q..4q+3, 4q+16..4q+19} ----
        union { f16x8_t v8; unsigned int u[4]; } bB;
        bB.u[0] = isq0 ? re.x : c1;
        bB.u[1] = isq0 ? re.y : 0u;
        bB.u[2] = isq0 ? re.z : 0u;
        bB.u[3] = isq0 ? re.w : 0u;

        f32x4_t z4 = {0.f, 0.f, 0.f, 0.f};
        f32x4_t h0 = __builtin_amdgcn_mfma_f32_16x16x32_f16(aW1_0, bB.v8, z4, 0, 0, 0);
        f32x4_t h1 = __builtin_amdgcn_mfma_f32_16x16x32_f16(aW1_1, bB.v8, z4, 0, 0, 0);

        f16x2_t hp0 = pkh(fmaxf(h0[0], 0.f), fmaxf(h0[1], 0.f));
        f16x2_t hp1 = pkh(fmaxf(h0[2], 0.f), fmaxf(h0[3], 0.f));
        f16x2_t hp2 = pkh(fmaxf(h1[0], 0.f), fmaxf(h1[1], 0.f));
        f16x2_t hp3 = pkh(fmaxf(h1[2], 0.f), fmaxf(h1[3], 0.f));

        // ---- b2-fold A fragment: adjacent pairs, half selected by q parity ----
        union { f16x8_t v8; unsigned int u[4]; } xb;
        xb.u[0] = qodd ? pr[4] : pr[0];
        xb.u[1] = qodd ? pr[5] : pr[1];
        xb.u[2] = qodd ? pr[6] : pr[2];
        xb.u[3] = qodd ? pr[7] : pr[3];

        // ---- K loop: A = h_j * dup(x_s) via v_perm + v_pk_mul_f16, two acc chains ----
        f32x4_t acc0 = {0.f, 0.f, 0.f, 0.f};
        f32x4_t acc1 = {0.f, 0.f, 0.f, 0.f};
        union { f16x8_t v8; f16x2_t v2[4]; } afr;
#pragma unroll
        for (int s2 = 0; s2 < 8; ++s2) {
            const unsigned int pp = pr[s2];
            f16x2_t xlo = dup_lo(pp);
            afr.v2[0] = hp0 * xlo;
            afr.v2[1] = hp1 * xlo;
            afr.v2[2] = hp2 * xlo;
            afr.v2[3] = hp3 * xlo;
            acc0 = __builtin_amdgcn_mfma_f32_16x16x32_f16(afr.v8, bW2[2 * s2], acc0, 0, 0, 0);
            f16x2_t xhi = dup_hi(pp);
            afr.v2[0] = hp0 * xhi;
            afr.v2[1] = hp1 * xhi;
            afr.v2[2] = hp2 * xhi;
            afr.v2[3] = hp3 * xhi;
            acc1 = __builtin_amdgcn_mfma_f32_16x16x32_f16(afr.v8, bW2[2 * s2 + 1], acc1, 0, 0, 0);
        }
        acc0 = __builtin_amdgcn_mfma_f32_16x16x32_f16(xb.v8, bW2[16], acc0, 0, 0, 0);

        const float rr0 = acc0[0] + acc1[0];
        const float rr1 = acc0[1] + acc1[1];
        const float rr2 = acc0[2] + acc1[2];
        const float rr3 = acc0[3] + acc1[3];
        if (EXACT) {
            atomicAdd(outc + (size_t)t0 * 16, rr0);
            atomicAdd(outc + (size_t)t1 * 16, rr1);
            atomicAdd(outc + (size_t)t2 * 16, rr2);
            atomicAdd(outc + (size_t)t3 * 16, rr3);
        } else {
            const int eb = g * 16 + q * 4;
            if (eb + 0 < n_edges) atomicAdd(outc + (size_t)t0 * 16, rr0);
            if (eb + 1 < n_edges) atomicAdd(outc + (size_t)t1 * 16, rr1);
            if (eb + 2 < n_edges) atomicAdd(outc + (size_t)t2 * 16, rr2);
            if (eb + 3 < n_edges) atomicAdd(outc + (size_t)t3 * 16, rr3);
        }
    }
}

// ============ fallback (ws too small): r13 direct kernel, raw loads ============
__global__ __launch_bounds__(256) void edge_fallback_kernel(
    const float* __restrict__ x, const float* __restrict__ efeat,
    const int* __restrict__ idx_i, const int* __restrict__ idx_j,
    const _Float16* __restrict__ tab, float* __restrict__ out,
    int n_edges, int n_groups)
{
    const int lane = threadIdx.x & 63;
    const int q = lane >> 4;
    const int c = lane & 15;
    const f16x8_t* w1f = reinterpret_cast<const f16x8_t*>(tab) + lane;
    const f16x8_t aW1_0 = w1f[0];
    const f16x8_t aW1_1 = w1f[64];
    const f16x8_t* w2f = reinterpret_cast<const f16x8_t*>(tab + 1024) + lane;
    f16x8_t bW2[17];
#pragma unroll
    for (int s = 0; s < 17; ++s) bW2[s] = w2f[s * 64];
    const unsigned int c1 = (q == 1) ? 0x00003C00u : 0u;
    const bool isq0 = (q == 0);
    const bool qodd = (q & 1);
    float* const outc = out + c;

    for (int g = blockIdx.x * 4 + (threadIdx.x >> 6); g < n_groups; g += gridDim.x * 4) {
        int eid = g * 16 + c;
        bool va = (eid < n_edges);
        int el = va ? eid : (n_edges - 1);
        int j = idx_j[el];
        float4 X0 = LD4(x + (size_t)j*16), X1 = LD4(x + (size_t)j*16 + 4);
        float4 X2 = LD4(x + (size_t)j*16 + 8), X3 = LD4(x + (size_t)j*16 + 12);
        const float* ep = efeat + (size_t)el * 8;
        float4 E0 = LD4(ep), E1 = LD4(ep + 4);
        int t0, t1, t2, t3;
        {
            const int eb = g * 16 + q * 4;
            t0 = (eb + 0 < n_edges) ? idx_i[eb + 0] : 0;
            t1 = (eb + 1 < n_edges) ? idx_i[eb + 1] : 0;
            t2 = (eb + 2 < n_edges) ? idx_i[eb + 2] : 0;
            t3 = (eb + 3 < n_edges) ? idx_i[eb + 3] : 0;
        }
        union { f16x8_t v8; unsigned int u[4]; } bB;
        bB.u[0] = isq0 ? pkrtz(E0.x, E0.y) : c1;
        bB.u[1] = isq0 ? pkrtz(E0.z, E0.w) : 0u;
        bB.u[2] = isq0 ? pkrtz(E1.x, E1.y) : 0u;
        bB.u[3] = isq0 ? pkrtz(E1.z, E1.w) : 0u;
        f32x4_t z4 = {0.f, 0.f, 0.f, 0.f};
        f32x4_t h0 = __builtin_amdgcn_mfma_f32_16x16x32_f16(aW1_0, bB.v8, z4, 0, 0, 0);
        f32x4_t h1 = __builtin_amdgcn_mfma_f32_16x16x32_f16(aW1_1, bB.v8, z4, 0, 0, 0);
        f16x2_t hp0 = pkh(fmaxf(h0[0], 0.f), fmaxf(h0[1], 0.f));
        f16x2_t hp1 = pkh(fmaxf(h0[2], 0.f), fmaxf(h0[3], 0.f));
        f16x2_t hp2 = pkh(fmaxf(h1[0], 0.f), fmaxf(h1[1], 0.f));
        f16x2_t hp3 = pkh(fmaxf(h1[2], 0.f), fmaxf(h1[3], 0.f));
        float xf[16];
        xf[0]=X0.x; xf[1]=X0.y; xf[2]=X0.z; xf[3]=X0.w;
        xf[4]=X1.x; xf[5]=X1.y; xf[6]=X1.z; xf[7]=X1.w;
        xf[8]=X2.x; xf[9]=X2.y; xf[10]=X2.z; xf[11]=X2.w;
        xf[12]=X3.x; xf[13]=X3.y; xf[14]=X3.z; xf[15]=X3.w;
        if (!va) { for (int t = 0; t < 16; ++t) xf[t] = 0.f; }
        f16x2_t xss[16];
#pragma unroll
        for (int f = 0; f < 16; ++f) xss[f] = pkh(xf[f], xf[f]);
        union { f16x8_t v8; unsigned int u[4]; } xb;
        xb.u[0] = pkrtz(qodd ? xf[8]  : xf[0], qodd ? xf[9]  : xf[1]);
        xb.u[1] = pkrtz(qodd ? xf[10] : xf[2], qodd ? xf[11] : xf[3]);
        xb.u[2] = pkrtz(qodd ? xf[12] : xf[4], qodd ? xf[13] : xf[5]);
        xb.u[3] = pkrtz(qodd ? xf[14] : xf[6], qodd ? xf[15] : xf[7]);
        f32x4_t acc0 = {0.f,0.f,0.f,0.f}, acc1 = {0.f,0.f,0.f,0.f};
        union { f16x8_t v8; f16x2_t v2[4]; } afr;
#pragma unroll
        for (int s = 0; s < 16; s += 2) {
            f16x2_t xs2 = xss[s];
            afr.v2[0] = hp0 * xs2; afr.v2[1] = hp1 * xs2;
            afr.v2[2] = hp2 * xs2; afr.v2[3] = hp3 * xs2;
            acc0 = __builtin_amdgcn_mfma_f32_16x16x32_f16(afr.v8, bW2[s], acc0, 0, 0, 0);
            xs2 = xss[s + 1];
            afr.v2[0] = hp0 * xs2; afr.v2[1] = hp1 * xs2;
            afr.v2[2] = hp2 * xs2; afr.v2[3] = hp3 * xs2;
            acc1 = __builtin_amdgcn_mfma_f32_16x16x32_f16(afr.v8, bW2[s + 1], acc1, 0, 0, 0);
        }
        acc0 = __builtin_amdgcn_mfma_f32_16x16x32_f16(xb.v8, bW2[16], acc0, 0, 0, 0);
        const float rr0 = acc0[0] + acc1[0];
        const float rr1 = acc0[1] + acc1[1];
        const float rr2 = acc0[2] + acc1[2];
        const float rr3 = acc0[3] + acc1[3];
        const int eb = g * 16 + q * 4;
        if (eb + 0 < n_edges) atomicAdd(outc + (size_t)t0 * 16, rr0);
        if (eb + 1 < n_edges) atomicAdd(outc + (size_t)t1 * 16, rr1);
        if (eb + 2 < n_edges) atomicAdd(outc + (size_t)t2 * 16, rr2);
        if (eb + 3 < n_edges) atomicAdd(outc + (size_t)t3 * 16, rr3);
    }
}

extern "C" void kernel_launch(void* const* d_in, const int* in_sizes, int n_in,
                              void* d_out, int out_size, void* d_ws, size_t ws_size,
                              hipStream_t stream) {
    const float* x     = (const float*)d_in[0];
    const float* e     = (const float*)d_in[1];
    const int*   idx_i = (const int*)d_in[2];
    const int*   idx_j = (const int*)d_in[3];
    const float* W1    = (const float*)d_in[4];
    const float* b1    = (const float*)d_in[5];
    const float* W2    = (const float*)d_in[6];
    const float* b2    = (const float*)d_in[7];
    const float* rootk = (const float*)d_in[8];
    const float* bias  = (const float*)d_in[9];

    int n_nodes  = in_sizes[0] / 16;
    int n_edges  = in_sizes[2];
    int n_groups = (n_edges + 15) / 16;

    float* out = (float*)d_out;
    _Float16* tab = (_Float16*)d_ws;
    unsigned int* rec32 = (unsigned int*)((char*)d_ws + (1u << 20));
    unsigned int* ef16  = (unsigned int*)((char*)d_ws + (20u << 20));

    size_t need = (20u << 20) + (size_t)n_edges * 16;
    const int use_pre = (ws_size >= need) ? 1 : 0;

    int root_blocks = (n_nodes + 255) / 256;
    prep_kernel<<<root_blocks + 1, 256, 0, stream>>>(x, W1, b1, W2, b2, rootk, bias,
                                                     out, tab, n_nodes, root_blocks);

    if (use_pre) {
        int gblocks = (n_edges + 255) / 256;
        prepg_kernel<<<gblocks, 256, 0, stream>>>(x, e, idx_j, rec32, ef16, n_edges);
        if ((n_edges & 15) == 0)
            edge_pre_kernel<1><<<1024, 256, 0, stream>>>(rec32, ef16, idx_i, tab, out,
                                                         n_edges, n_groups);
        else
            edge_pre_kernel<0><<<1024, 256, 0, stream>>>(rec32, ef16, idx_i, tab, out,
                                                         n_edges, n_groups);
    } else {
        edge_fallback_kernel<<<1024, 256, 0, stream>>>(x, e, idx_i, idx_j, tab, out,
                                                       n_edges, n_groups);
    }
}

// Round 16
// 48.320 us; speedup vs baseline: 2.0154x; 1.1622x over previous
//
#include <hip/hip_runtime.h>

typedef __attribute__((ext_vector_type(8))) _Float16 f16x8_t;  // MFMA A/B operand (4 VGPRs)
typedef __attribute__((ext_vector_type(2))) _Float16 f16x2_t;  // packed f16 pair
typedef __attribute__((ext_vector_type(4))) float f32x4_t;     // MFMA accumulator

__device__ __forceinline__ f16x2_t pkh(float lo, float hi) {
    return __builtin_bit_cast(f16x2_t, __builtin_amdgcn_cvt_pkrtz(lo, hi));
}
__device__ __forceinline__ unsigned int pkrtz(float lo, float hi) {
    return __builtin_bit_cast(unsigned int, __builtin_amdgcn_cvt_pkrtz(lo, hi));
}
__device__ __forceinline__ f16x2_t dup_lo(unsigned int u) {
    return __builtin_bit_cast(f16x2_t, __builtin_amdgcn_perm(u, u, 0x01000100u));
}
__device__ __forceinline__ f16x2_t dup_hi(unsigned int u) {
    return __builtin_bit_cast(f16x2_t, __builtin_amdgcn_perm(u, u, 0x03020302u));
}

#define LD4(p) (*reinterpret_cast<const float4*>(p))

__device__ __forceinline__ float4 shfl4(float4 v, int src) {
    float4 r;
    r.x = __shfl(v.x, src); r.y = __shfl(v.y, src);
    r.z = __shfl(v.z, src); r.w = __shfl(v.w, src);
    return r;
}

// d_ws layout (f16): [0..1024) W1p h-MFMA A-frags; [1024..9728) W2p B-frags.

// ============ kernel 0: {root-init | tab prep} ============
__global__ __launch_bounds__(256) void prep_kernel(
    const float* __restrict__ x,
    const float* __restrict__ W1,      // [8,32]
    const float* __restrict__ b1,      // [32]
    const float* __restrict__ W2,      // [32,256]
    const float* __restrict__ b2,      // [256]
    const float* __restrict__ rootk,   // [16,16]
    const float* __restrict__ bias,    // [16]
    float* __restrict__ out,           // [N,16]
    _Float16* __restrict__ tab,
    int n_nodes, int root_blocks)
{
    const int tid = threadIdx.x;
    const int bid = blockIdx.x;

    if (bid < root_blocks) {
        __shared__ float sR[256];
        __shared__ float sB[16];
        if (tid < 256) sR[tid] = rootk[tid];
        if (tid < 16)  sB[tid] = bias[tid];
        __syncthreads();

        int nid = bid * 256 + tid;
        if (nid >= n_nodes) return;

        const float* xp = x + (size_t)nid * 16;
        float xf[16];
#pragma unroll
        for (int f = 0; f < 16; f += 4) {
            float4 v = LD4(xp + f);
            xf[f] = v.x; xf[f + 1] = v.y; xf[f + 2] = v.z; xf[f + 3] = v.w;
        }
        float o[16];
#pragma unroll
        for (int cc = 0; cc < 16; ++cc) o[cc] = sB[cc];
#pragma unroll
        for (int f = 0; f < 16; ++f) {
            float p = xf[f];
#pragma unroll
            for (int cc = 0; cc < 16; ++cc)
                o[cc] = fmaf(p, sR[f * 16 + cc], o[cc]);
        }
        float* dst = out + (size_t)nid * 16;
#pragma unroll
        for (int cc = 0; cc < 16; cc += 4)
            *reinterpret_cast<float4*>(dst + cc) = make_float4(o[cc], o[cc+1], o[cc+2], o[cc+3]);
    } else {
        for (int it = tid; it < 64 * 19; it += 256) {
            int grp  = it >> 6;         // 0,1 -> W1p halves; 2..18 -> W2p steps
            int lane = it & 63;
            int q = lane >> 4, cc = lane & 15;
            union { _Float16 h[8]; uint4 u; } pk;
            if (grp < 2) {
                int hh = grp;
#pragma unroll
                for (int j = 0; j < 8; ++j) {
                    float v = 0.f;
                    if (q == 0)              v = W1[j * 32 + cc + 16 * hh];
                    else if (q == 1 && j==0) v = b1[cc + 16 * hh];
                    pk.h[j] = (_Float16)v;
                }
                *reinterpret_cast<uint4*>(tab + ((size_t)hh * 64 + lane) * 8) = pk.u;
            } else {
                int s = grp - 2;        // K-step
#pragma unroll
                for (int j = 0; j < 8; ++j) {
                    float v;
                    if (s < 16) {
                        int hd = (j < 4) ? (4 * q + j) : (4 * q + 12 + j);  // perm
                        v = W2[hd * 256 + s * 16 + cc];
                    } else {
                        v = (q < 2) ? b2[(q * 8 + j) * 16 + cc] : 0.f;       // b2 fold
                    }
                    pk.h[j] = (_Float16)v;
                }
                *reinterpret_cast<uint4*>(tab + 1024 + ((size_t)s * 64 + lane) * 8) = pk.u;
            }
        }
    }
}

// ============ kernel 1: edge MFMA — ALL loads before ANY atomic, one 4-group run/wave ============
template<int EXACT>
__global__ __launch_bounds__(256) void edge_v16_kernel(
    const float* __restrict__ x,       // [N,16]
    const float* __restrict__ efeat,   // [E,8]
    const int*   __restrict__ idx_i,
    const int*   __restrict__ idx_j,
    const _Float16* __restrict__ tab,
    float* __restrict__ out,           // [N,16], pre-initialized with root term
    int n_edges, int n_groups)
{
    const int lane = threadIdx.x & 63;
    const int q = lane >> 4;
    const int c = lane & 15;

    // ---- per-wave fragment preload (registers, f16) ----
    const f16x8_t* w1f = reinterpret_cast<const f16x8_t*>(tab) + lane;
    const f16x8_t aW1_0 = w1f[0];
    const f16x8_t aW1_1 = w1f[64];
    const f16x8_t* w2f = reinterpret_cast<const f16x8_t*>(tab + 1024) + lane;
    f16x8_t bW2[17];
#pragma unroll
    for (int s = 0; s < 17; ++s) bW2[s] = w2f[s * 64];

    const unsigned int c1 = (q == 1) ? 0x00003C00u : 0u;   // f16(1.0) one-hot for b1 row
    const bool isq0 = (q == 0);
    const bool qodd = (q & 1);
    float* const outc = out + c;

    const int wid = blockIdx.x * 4 + (threadIdx.x >> 6);
    const int g0  = wid * 4;
    if (g0 >= n_groups) return;
    const int rem  = n_groups - g0;    // wave-uniform, >= 1
    const int base = g0 * 16;

    // ======== PHASE 1: every VMEM load of this wave, no atomics yet ========
    int el = base + lane;                      // lane owns edge base+lane (covers 4 groups)
    if (el >= n_edges) el = n_edges - 1;
    const int jall = idx_j[el];
    const int iall = idx_i[el];
    const float* ep = efeat + (size_t)el * 8;
    const float4 Eo0 = LD4(ep);
    const float4 Eo1 = LD4(ep + 4);

    // gathers: lane (q,c) loads quarter q of source row of edge (k, c)
    const int js0 = __shfl(jall, c);
    const float4 XQ0 = LD4(x + (size_t)js0 * 16 + q * 4);
    float4 XQ1 = XQ0, XQ2 = XQ0, XQ3 = XQ0;
    if (rem > 1) { int j1 = __shfl(jall, 16 + c); XQ1 = LD4(x + (size_t)j1 * 16 + q * 4); }
    if (rem > 2) { int j2 = __shfl(jall, 32 + c); XQ2 = LD4(x + (size_t)j2 * 16 + q * 4); }
    if (rem > 3) { int j3 = __shfl(jall, 48 + c); XQ3 = LD4(x + (size_t)j3 * 16 + q * 4); }

    // own edge features -> f16 pairs (shfl'd to q0 lanes per group later)
    const unsigned int eo0 = pkrtz(Eo0.x, Eo0.y);
    const unsigned int eo1 = pkrtz(Eo0.z, Eo0.w);
    const unsigned int eo2 = pkrtz(Eo1.x, Eo1.y);
    const unsigned int eo3 = pkrtz(Eo1.z, Eo1.w);

    // ======== PHASE 2: register-only compute (lgkm shfls + MFMA, no VMEM) ========
    float rr00=0,rr01=0,rr02=0,rr03=0, rr10=0,rr11=0,rr12=0,rr13=0;
    float rr20=0,rr21=0,rr22=0,rr23=0, rr30=0,rr31=0,rr32=0,rr33=0;

    auto compute = [&](int k16, float4 XQ, float& o0, float& o1, float& o2, float& o3) {
        // redistribute quarters: full source row of edge (k, c)
        float4 X0 = shfl4(XQ, c);
        float4 X1 = shfl4(XQ, c + 16);
        float4 X2 = shfl4(XQ, c + 32);
        float4 X3 = shfl4(XQ, c + 48);
        // (garbage rows for invalid edges corrupt only their own D rows; atomics guarded)

        // x as adjacent f16 pairs
        unsigned int pr0 = pkrtz(X0.x, X0.y), pr1 = pkrtz(X0.z, X0.w);
        unsigned int pr2 = pkrtz(X1.x, X1.y), pr3 = pkrtz(X1.z, X1.w);
        unsigned int pr4 = pkrtz(X2.x, X2.y), pr5 = pkrtz(X2.z, X2.w);
        unsigned int pr6 = pkrtz(X3.x, X3.y), pr7 = pkrtz(X3.z, X3.w);

        // h via MFMA: B col c = e of edge (k, c), from lane k16+c
        union { f16x8_t v8; unsigned int u[4]; } bB;
        {
            unsigned int u0 = __shfl(eo0, k16 + c);
            unsigned int u1 = __shfl(eo1, k16 + c);
            unsigned int u2 = __shfl(eo2, k16 + c);
            unsigned int u3 = __shfl(eo3, k16 + c);
            bB.u[0] = isq0 ? u0 : c1;
            bB.u[1] = isq0 ? u1 : 0u;
            bB.u[2] = isq0 ? u2 : 0u;
            bB.u[3] = isq0 ? u3 : 0u;
        }
        f32x4_t z4 = {0.f, 0.f, 0.f, 0.f};
        f32x4_t h0 = __builtin_amdgcn_mfma_f32_16x16x32_f16(aW1_0, bB.v8, z4, 0, 0, 0);
        f32x4_t h1 = __builtin_amdgcn_mfma_f32_16x16x32_f16(aW1_1, bB.v8, z4, 0, 0, 0);

        f16x2_t hp0 = pkh(fmaxf(h0[0], 0.f), fmaxf(h0[1], 0.f));
        f16x2_t hp1 = pkh(fmaxf(h0[2], 0.f), fmaxf(h0[3], 0.f));
        f16x2_t hp2 = pkh(fmaxf(h1[0], 0.f), fmaxf(h1[1], 0.f));
        f16x2_t hp3 = pkh(fmaxf(h1[2], 0.f), fmaxf(h1[3], 0.f));

        // b2-fold A fragment
        union { f16x8_t v8; unsigned int u[4]; } xb;
        xb.u[0] = qodd ? pr4 : pr0;
        xb.u[1] = qodd ? pr5 : pr1;
        xb.u[2] = qodd ? pr6 : pr2;
        xb.u[3] = qodd ? pr7 : pr3;

        // K loop: A = h_j * dup(x_s), two acc chains
        f32x4_t acc0 = {0.f, 0.f, 0.f, 0.f};
        f32x4_t acc1 = {0.f, 0.f, 0.f, 0.f};
        union { f16x8_t v8; f16x2_t v2[4]; } afr;
        unsigned int prs[8] = {pr0, pr1, pr2, pr3, pr4, pr5, pr6, pr7};
#pragma unroll
        for (int s2 = 0; s2 < 8; ++s2) {
            const unsigned int pp = prs[s2];
            f16x2_t xlo = dup_lo(pp);
            afr.v2[0] = hp0 * xlo;
            afr.v2[1] = hp1 * xlo;
            afr.v2[2] = hp2 * xlo;
            afr.v2[3] = hp3 * xlo;
            acc0 = __builtin_amdgcn_mfma_f32_16x16x32_f16(afr.v8, bW2[2 * s2], acc0, 0, 0, 0);
            f16x2_t xhi = dup_hi(pp);
            afr.v2[0] = hp0 * xhi;
            afr.v2[1] = hp1 * xhi;
            afr.v2[2] = hp2 * xhi;
            afr.v2[3] = hp3 * xhi;
            acc1 = __builtin_amdgcn_mfma_f32_16x16x32_f16(afr.v8, bW2[2 * s2 + 1], acc1, 0, 0, 0);
        }
        acc0 = __builtin_amdgcn_mfma_f32_16x16x32_f16(xb.v8, bW2[16], acc0, 0, 0, 0);

        o0 = acc0[0] + acc1[0];
        o1 = acc0[1] + acc1[1];
        o2 = acc0[2] + acc1[2];
        o3 = acc0[3] + acc1[3];
    };

    compute(0, XQ0, rr00, rr01, rr02, rr03);
    if (rem > 1) compute(16, XQ1, rr10, rr11, rr12, rr13);
    if (rem > 2) compute(32, XQ2, rr20, rr21, rr22, rr23);
    if (rem > 3) compute(48, XQ3, rr30, rr31, rr32, rr33);

    // ======== PHASE 3: all atomics at the very end (no VMEM after) ========
    const int qr = q * 4;
#define SCATTER(k16, R0, R1, R2, R3)                                          \
    {                                                                         \
        int t0 = __shfl(iall, (k16) + qr + 0);                                \
        int t1 = __shfl(iall, (k16) + qr + 1);                                \
        int t2 = __shfl(iall, (k16) + qr + 2);                                \
        int t3 = __shfl(iall, (k16) + qr + 3);                                \
        if (EXACT) {                                                          \
            atomicAdd(outc + (size_t)t0 * 16, R0);                            \
            atomicAdd(outc + (size_t)t1 * 16, R1);                            \
            atomicAdd(outc + (size_t)t2 * 16, R2);                            \
            atomicAdd(outc + (size_t)t3 * 16, R3);                            \
        } else {                                                              \
            const int eb = base + (k16) + qr;                                 \
            if (eb + 0 < n_edges) atomicAdd(outc + (size_t)t0 * 16, R0);      \
            if (eb + 1 < n_edges) atomicAdd(outc + (size_t)t1 * 16, R1);      \
            if (eb + 2 < n_edges) atomicAdd(outc + (size_t)t2 * 16, R2);      \
            if (eb + 3 < n_edges) atomicAdd(outc + (size_t)t3 * 16, R3);      \
        }                                                                     \
    }

    SCATTER(0, rr00, rr01, rr02, rr03);
    if (rem > 1) SCATTER(16, rr10, rr11, rr12, rr13);
    if (rem > 2) SCATTER(32, rr20, rr21, rr22, rr23);
    if (rem > 3) SCATTER(48, rr30, rr31, rr32, rr33);
#undef SCATTER
}

extern "C" void kernel_launch(void* const* d_in, const int* in_sizes, int n_in,
                              void* d_out, int out_size, void* d_ws, size_t ws_size,
                              hipStream_t stream) {
    const float* x     = (const float*)d_in[0];
    const float* e     = (const float*)d_in[1];
    const int*   idx_i = (const int*)d_in[2];
    const int*   idx_j = (const int*)d_in[3];
    const float* W1    = (const float*)d_in[4];
    const float* b1    = (const float*)d_in[5];
    const float* W2    = (const float*)d_in[6];
    const float* b2    = (const float*)d_in[7];
    const float* rootk = (const float*)d_in[8];
    const float* bias  = (const float*)d_in[9];

    int n_nodes  = in_sizes[0] / 16;
    int n_edges  = in_sizes[2];
    int n_groups = (n_edges + 15) / 16;

    float* out = (float*)d_out;
    _Float16* tab = (_Float16*)d_ws;   // 19.5 KB used

    int root_blocks = (n_nodes + 255) / 256;
    prep_kernel<<<root_blocks + 1, 256, 0, stream>>>(x, W1, b1, W2, b2, rootk, bias,
                                                     out, tab, n_nodes, root_blocks);

    // one 4-group run per wave, 4 waves/block
    int waves  = (n_groups + 3) / 4;
    int blocks = (waves + 3) / 4;
    if ((n_edges & 15) == 0)
        edge_v16_kernel<1><<<blocks, 256, 0, stream>>>(x, e, idx_i, idx_j, tab, out,
                                                       n_edges, n_groups);
    else
        edge_v16_kernel<0><<<blocks, 256, 0, stream>>>(x, e, idx_i, idx_j, tab, out,
                                                       n_edges, n_groups);
}